// Round 4
// baseline (645.874 us; speedup 1.0000x reference)
//
#include <hip/hip_runtime.h>
#include <hip/hip_bf16.h>
#include <math.h>

constexpr int S   = 64;
constexpr int B   = 32;
constexpr int HID = 16;
constexpr int EMB = 32;
constexpr int V   = 50257;
constexpr int CH  = 2*HID;        // 32 = K (exactly two 32x32x16 MFMAs)
constexpr int IN  = EMB + HID;    // 48
constexpr int VPAD = 50272;       // 1571 * 32
constexpr int NT32 = VPAD/32;     // 1571 n-tiles
constexpr int MT32 = (S*B)/32;    // 64 m-tiles
constexpr int NSTRIP = 64;        // 64 strips x 32 block-rows = 2048 blocks
constexpr int NT_PER = (NT32 + NSTRIP - 1)/NSTRIP;   // 25
constexpr int NB_CONV = (VPAD*CH)/256;               // 6284 (exact)
constexpr int NB_XW   = (S*B)/4;                     // 512

typedef __attribute__((ext_vector_type(8)))  short bf16x8;   // 8 bf16 = 4 VGPRs
typedef __attribute__((ext_vector_type(16))) float f32x16;   // 32x32 accum

__device__ inline float bcast(float v, int l) {   // compile-time lane broadcast
    return __uint_as_float(__builtin_amdgcn_readlane(__float_as_uint(v), l));
}
__device__ inline float rcp_fast(float x) { return __builtin_amdgcn_rcpf(x); }

// ---- prep: W_ho->bf16 (pad rows>=V with 0), b_ho->fp32 (pad -30),
//            row_sums zero, and xw = emb-part of all 4 gates ---------------
__global__ __launch_bounds__(256) void kprep(
    const int* __restrict__ tok, const float* __restrict__ emb,
    const float* __restrict__ Wf, const float* __restrict__ bf,
    const float* __restrict__ Wi, const float* __restrict__ bi,
    const float* __restrict__ Wc, const float* __restrict__ bc,
    const float* __restrict__ Wo, const float* __restrict__ bo,
    const float* __restrict__ Who, const float* __restrict__ bho,
    __hip_bfloat16* __restrict__ WhoB, float* __restrict__ bhoP,
    float* __restrict__ xw, float* __restrict__ row_sums)
{
    int bid = blockIdx.x, t = threadIdx.x;
    if (bid < NB_CONV) {
        int i = bid*256 + t;                       // < VPAD*CH exactly
        int r = i >> 5;
        WhoB[i] = __float2bfloat16((r < V) ? Who[i] : 0.f);
        if (i < VPAD) bhoP[i] = (i < V) ? bho[i] : -30.f;
        if (i < S*B)  row_sums[i] = 0.f;
    } else {
        int grp = t >> 6, lane = t & 63;
        int sb  = (bid - NB_CONV)*4 + grp;
        __shared__ float e[4][EMB];
        if (lane < EMB) e[grp][lane] = emb[(long)tok[sb]*EMB + lane];
        __syncthreads();
        int g = lane >> 4, h = lane & 15;
        const float* W  = (g==0) ? Wf : (g==1) ? Wi : (g==2) ? Wc : Wo;
        const float* bv = (g==0) ? bf : (g==1) ? bi : (g==2) ? bc : bo;
        const float* wr = W + h*IN;
        float acc = bv[h];
        #pragma unroll
        for (int k = 0; k < EMB; ++k) acc += e[grp][k]*wr[k];
        xw[sb*64 + lane] = acc;
    }
}

// ---- k2: 32 blocks, each wave runs BOTH directions of one batch (2-way ILP).
// Single-exp activations: sigmoid via rcp_fast, tanh(x)=2*sigm(2x)-1.
// h-broadcasts via v_readlane (SGPR, ~3cy) instead of ds_bpermute (~30cy).
__global__ __launch_bounds__(64) void k2_scan(
    const float* __restrict__ xw,
    const float* __restrict__ Wf, const float* __restrict__ Wi,
    const float* __restrict__ Wc, const float* __restrict__ Wo,
    const float* __restrict__ h0, const float* __restrict__ C0,
    __hip_bfloat16* __restrict__ hcatB)
{
    int b    = blockIdx.x;           // 0..31
    int lane = threadIdx.x;
    int g = lane >> 4, hh = lane & 15;
    const float* W = (g==0) ? Wf : (g==1) ? Wi : (g==2) ? Wc : Wo;
    float U[HID];
    #pragma unroll
    for (int k = 0; k < HID; ++k) U[k] = W[hh*IN + EMB + k];
    float hA = h0[hh], CA = C0[hh];      // dir 0 (forward)
    float hB = h0[hh], CB = C0[hh];      // dir 1 (backward)
    int sbA = b, sbB = (S-1)*B + b;
    float xnA = xw[sbA*64 + lane];
    float xnB = xw[sbB*64 + lane];
    for (int step = 0; step < S; ++step) {
        float pA = xnA, pB = xnB;
        if (step + 1 < S) {                      // prefetch next x-contribs
            xnA = xw[(sbA + B)*64 + lane];
            xnB = xw[(sbB - B)*64 + lane];
        }
        if (g == 0) {                            // store h BEFORE update
            hcatB[sbA*CH + hh]       = __float2bfloat16(hA);
            hcatB[sbB*CH + HID + hh] = __float2bfloat16(hB);
        }
        float qA0=0.f,qA1=0.f,qA2=0.f,qA3=0.f;
        float qB0=0.f,qB1=0.f,qB2=0.f,qB3=0.f;
        #pragma unroll
        for (int k = 0; k < HID; k += 4) {       // 4 indep chains x 2 streams
            qA0 += U[k  ]*bcast(hA, k  );  qB0 += U[k  ]*bcast(hB, k  );
            qA1 += U[k+1]*bcast(hA, k+1);  qB1 += U[k+1]*bcast(hB, k+1);
            qA2 += U[k+2]*bcast(hA, k+2);  qB2 += U[k+2]*bcast(hB, k+2);
            qA3 += U[k+3]*bcast(hA, k+3);  qB3 += U[k+3]*bcast(hB, k+3);
        }
        pA += (qA0+qA1) + (qA2+qA3);
        pB += (qB0+qB1) + (qB2+qB3);
        // one exp + one rcp per stream: a = (g==2) ? tanh(p) : sigm(p)
        float tA = (g==2) ? pA+pA : pA;
        float tB = (g==2) ? pB+pB : pB;
        float eA = __expf(-tA), eB = __expf(-tB);
        float sA = rcp_fast(1.f + eA), sB = rcp_fast(1.f + eB);
        float aA = (g==2) ? sA+sA-1.f : sA;
        float aB = (g==2) ? sB+sB-1.f : sB;
        float fgA = __shfl(aA,      hh, 64), fgB = __shfl(aB,      hh, 64);
        float igA = __shfl(aA, 16 + hh, 64), igB = __shfl(aB, 16 + hh, 64);
        float cgA = __shfl(aA, 32 + hh, 64), cgB = __shfl(aB, 32 + hh, 64);
        float ogA = __shfl(aA, 48 + hh, 64), ogB = __shfl(aB, 48 + hh, 64);
        CA = fgA*CA + igA*cgA;
        CB = fgB*CB + igB*cgB;
        float e2A = __expf(-(CA+CA));            // tanh(C) = 2*sigm(2C)-1
        float e2B = __expf(-(CB+CB));
        hA = ogA*(2.f*rcp_fast(1.f + e2A) - 1.f);
        hB = ogB*(2.f*rcp_fast(1.f + e2B) - 1.f);
        sbA += B; sbB -= B;
    }
}

// ---- kA: sum exp(logit) per row. 32x32 MFMA, bias seeded in accum. -------
// |logit| <= 8.25 -> fp32 sum-exp safe, no max shift. B-tile prefetched.
// 128-thr blocks (2 waves), grid (64,32)=2048 = 8 blocks/CU uniform ->
// 16 waves/CU: double the TLP of the 256-thr/512-block shape (latency fix).
__global__ __launch_bounds__(128) void kA(
    const __hip_bfloat16* __restrict__ hcatB, const __hip_bfloat16* __restrict__ WhoB,
    const float* __restrict__ bhoP, float* __restrict__ row_sums)
{
    int t = threadIdx.x, w = t >> 6, lane = t & 63;
    int l31 = lane & 31, half = lane >> 5;
    int r0 = (blockIdx.y*2 + w)*32;
    int n0 = blockIdx.x*NT_PER;
    if (n0 >= NT32) return;
    int n1 = (n0 + NT_PER < NT32) ? n0 + NT_PER : NT32;
    const short* hp = (const short*)hcatB + (r0 + l31)*CH + half*8;
    bf16x8 a0 = *(const bf16x8*)hp;
    bf16x8 a1 = *(const bf16x8*)(hp + 16);
    float acc[16];
    #pragma unroll
    for (int r = 0; r < 16; ++r) acc[r] = 0.f;
    const short* bp = (const short*)WhoB + (long)(n0*32 + l31)*CH + half*8;
    bf16x8 b0 = *(const bf16x8*)bp;
    bf16x8 b1 = *(const bf16x8*)(bp + 16);
    float  bv = bhoP[n0*32 + l31];
    for (int nt = n0; nt < n1; ++nt) {
        int ntn = (nt + 1 < n1) ? nt + 1 : nt;          // prefetch next tile
        const short* bpn = (const short*)WhoB + (long)(ntn*32 + l31)*CH + half*8;
        bf16x8 nb0 = *(const bf16x8*)bpn;
        bf16x8 nb1 = *(const bf16x8*)(bpn + 16);
        float  nbv = bhoP[ntn*32 + l31];
        f32x16 d;
        #pragma unroll
        for (int r = 0; r < 16; ++r) d[r] = bv;         // bias-seeded accum
        d = __builtin_amdgcn_mfma_f32_32x32x16_bf16(a0, b0, d, 0, 0, 0);
        d = __builtin_amdgcn_mfma_f32_32x32x16_bf16(a1, b1, d, 0, 0, 0);
        #pragma unroll
        for (int r = 0; r < 16; ++r) acc[r] += __expf(d[r]);
        b0 = nb0; b1 = nb1; bv = nbv;
    }
    #pragma unroll
    for (int off = 1; off < 32; off <<= 1) {        // reduce over 32-lane half
        #pragma unroll
        for (int r = 0; r < 16; ++r) acc[r] += __shfl_xor(acc[r], off);
    }
    if (l31 == 0) {
        #pragma unroll
        for (int r = 0; r < 16; ++r)
            atomicAdd(&row_sums[r0 + (r&3) + 8*(r>>2) + 4*half], acc[r]);
    }
}

// ---- kB: recompute logits, seed accum with (bias - logZ), store ----------
// Store pattern: per reg, each 32-lane half writes 128B contiguous. Regular
// (cached) stores: L2 write-combines the row-misaligned straddles; nt stores
// caused 2.2 GB of RMW fetch (round-1 post-mortem) -- do NOT bypass L2 here.
// Same 128-thr/2048-block shape as kA (16 waves/CU).
__global__ __launch_bounds__(128) void kB(
    const __hip_bfloat16* __restrict__ hcatB, const __hip_bfloat16* __restrict__ WhoB,
    const float* __restrict__ bhoP, const float* __restrict__ row_sums,
    float* __restrict__ out)
{
    int t = threadIdx.x, w = t >> 6, lane = t & 63;
    int l31 = lane & 31, half = lane >> 5;
    int r0 = (blockIdx.y*2 + w)*32;
    int n0 = blockIdx.x*NT_PER;
    if (n0 >= NT32) return;
    int n1 = (n0 + NT_PER < NT32) ? n0 + NT_PER : NT32;
    const short* hp = (const short*)hcatB + (r0 + l31)*CH + half*8;
    bf16x8 a0 = *(const bf16x8*)hp;
    bf16x8 a1 = *(const bf16x8*)(hp + 16);
    float    lzr[16];
    unsigned obase[16];
    #pragma unroll
    for (int r = 0; r < 16; ++r) {
        int row = r0 + (r&3) + 8*(r>>2) + 4*half;
        lzr[r]   = logf(row_sums[row]);
        obase[r] = (unsigned)row*V + l31;           // max < 103M, fits u32
    }
    const short* bp = (const short*)WhoB + (long)(n0*32 + l31)*CH + half*8;
    bf16x8 b0 = *(const bf16x8*)bp;
    bf16x8 b1 = *(const bf16x8*)(bp + 16);
    float  bv = bhoP[n0*32 + l31];
    for (int nt = n0; nt < n1; ++nt) {
        int v0 = nt*32;
        int ntn = (nt + 1 < n1) ? nt + 1 : nt;          // prefetch next tile
        const short* bpn = (const short*)WhoB + (long)(ntn*32 + l31)*CH + half*8;
        bf16x8 nb0 = *(const bf16x8*)bpn;
        bf16x8 nb1 = *(const bf16x8*)(bpn + 16);
        float  nbv = bhoP[ntn*32 + l31];
        f32x16 d;
        #pragma unroll
        for (int r = 0; r < 16; ++r) d[r] = bv - lzr[r];   // seed epilogue
        d = __builtin_amdgcn_mfma_f32_32x32x16_bf16(a0, b0, d, 0, 0, 0);
        d = __builtin_amdgcn_mfma_f32_32x32x16_bf16(a1, b1, d, 0, 0, 0);
        if (v0 + l31 < V) {
            #pragma unroll
            for (int r = 0; r < 16; ++r) out[obase[r] + v0] = d[r];
        }
        b0 = nb0; b1 = nb1; bv = nbv;
    }
}

extern "C" void kernel_launch(void* const* d_in, const int* in_sizes, int n_in,
                              void* d_out, int out_size, void* d_ws, size_t ws_size,
                              hipStream_t stream)
{
    const int*   tok = (const int*)d_in[0];
    const float* emb = (const float*)d_in[1];
    const float* Wf  = (const float*)d_in[2];
    const float* bf  = (const float*)d_in[3];
    const float* Wi  = (const float*)d_in[4];
    const float* bi  = (const float*)d_in[5];
    const float* Wc  = (const float*)d_in[6];
    const float* bc  = (const float*)d_in[7];
    const float* Wo  = (const float*)d_in[8];
    const float* bo  = (const float*)d_in[9];
    const float* Who = (const float*)d_in[10];
    const float* bho = (const float*)d_in[11];
    const float* h0  = (const float*)d_in[12];
    const float* C0  = (const float*)d_in[13];
    float* out = (float*)d_out;

    char* p = (char*)d_ws;
    __hip_bfloat16* WhoB  = (__hip_bfloat16*)p; p += (size_t)VPAD*CH*2;  // 3.2 MB
    __hip_bfloat16* hcatB = (__hip_bfloat16*)p; p += (size_t)S*B*CH*2;   // 128 KB
    float* bhoP     = (float*)p; p += (size_t)VPAD*4;
    float* xw       = (float*)p; p += (size_t)S*B*64*4;
    float* row_sums = (float*)p;

    kprep<<<dim3(NB_CONV + NB_XW), dim3(256), 0, stream>>>(
        tok, emb, Wf, bf, Wi, bi, Wc, bc, Wo, bo, Who, bho,
        WhoB, bhoP, xw, row_sums);
    k2_scan<<<dim3(32), dim3(64), 0, stream>>>(xw, Wf, Wi, Wc, Wo, h0, C0, hcatB);
    dim3 g(NSTRIP, MT32/2);   // (64, 32) = 2048 blocks = 8/CU uniform
    kA<<<g, dim3(128), 0, stream>>>(hcatB, WhoB, bhoP, row_sums);
    kB<<<g, dim3(128), 0, stream>>>(hcatB, WhoB, bhoP, row_sums, out);
}

// Round 5
// 596.060 us; speedup vs baseline: 1.0836x; 1.0836x over previous
//
#include <hip/hip_runtime.h>
#include <hip/hip_bf16.h>
#include <math.h>

constexpr int S   = 64;
constexpr int B   = 32;
constexpr int HID = 16;
constexpr int EMB = 32;
constexpr int V   = 50257;
constexpr int CH  = 2*HID;        // 32 = K (exactly two 32x32x16 MFMAs)
constexpr int IN  = EMB + HID;    // 48
constexpr int VPAD = 50272;       // 1571 * 32
constexpr int NT32 = VPAD/32;     // 1571 n-tiles
constexpr int MT32 = (S*B)/32;    // 64 m-tiles
constexpr int NSTRIP = 32;        // 512 blocks = exactly 2/CU, uniform (no tail)
constexpr int NT_PER = (NT32 + NSTRIP - 1)/NSTRIP;   // 50
constexpr int GRP = 5;            // 50 = 5 x 10 exact per full strip
constexpr int NB_CONV = (VPAD*CH)/256;               // 6284 (exact)
constexpr int NB_XW   = (S*B)/4;                     // 512

typedef __attribute__((ext_vector_type(8)))  short bf16x8;   // 8 bf16 = 4 VGPRs
typedef __attribute__((ext_vector_type(16))) float f32x16;   // 32x32 accum

__device__ inline float bcast(float v, int l) {   // compile-time lane broadcast
    return __uint_as_float(__builtin_amdgcn_readlane(__float_as_uint(v), l));
}
__device__ inline float rcp_fast(float x) { return __builtin_amdgcn_rcpf(x); }

// ---- prep: W_ho->bf16 (pad rows>=V with 0), b_ho->fp32 (pad -30),
//            row_sums zero, and xw = emb-part of all 4 gates ---------------
__global__ __launch_bounds__(256) void kprep(
    const int* __restrict__ tok, const float* __restrict__ emb,
    const float* __restrict__ Wf, const float* __restrict__ bf,
    const float* __restrict__ Wi, const float* __restrict__ bi,
    const float* __restrict__ Wc, const float* __restrict__ bc,
    const float* __restrict__ Wo, const float* __restrict__ bo,
    const float* __restrict__ Who, const float* __restrict__ bho,
    __hip_bfloat16* __restrict__ WhoB, float* __restrict__ bhoP,
    float* __restrict__ xw, float* __restrict__ row_sums)
{
    int bid = blockIdx.x, t = threadIdx.x;
    if (bid < NB_CONV) {
        int i = bid*256 + t;                       // < VPAD*CH exactly
        int r = i >> 5;
        WhoB[i] = __float2bfloat16((r < V) ? Who[i] : 0.f);
        if (i < VPAD) bhoP[i] = (i < V) ? bho[i] : -30.f;
        if (i < S*B)  row_sums[i] = 0.f;
    } else {
        int grp = t >> 6, lane = t & 63;
        int sb  = (bid - NB_CONV)*4 + grp;
        __shared__ float e[4][EMB];
        if (lane < EMB) e[grp][lane] = emb[(long)tok[sb]*EMB + lane];
        __syncthreads();
        int g = lane >> 4, h = lane & 15;
        const float* W  = (g==0) ? Wf : (g==1) ? Wi : (g==2) ? Wc : Wo;
        const float* bv = (g==0) ? bf : (g==1) ? bi : (g==2) ? bc : bo;
        const float* wr = W + h*IN;
        float acc = bv[h];
        #pragma unroll
        for (int k = 0; k < EMB; ++k) acc += e[grp][k]*wr[k];
        xw[sb*64 + lane] = acc;
    }
}

// ---- k2: 32 blocks, each wave runs BOTH directions of one batch (2-way ILP).
__global__ __launch_bounds__(64) void k2_scan(
    const float* __restrict__ xw,
    const float* __restrict__ Wf, const float* __restrict__ Wi,
    const float* __restrict__ Wc, const float* __restrict__ Wo,
    const float* __restrict__ h0, const float* __restrict__ C0,
    __hip_bfloat16* __restrict__ hcatB)
{
    int b    = blockIdx.x;           // 0..31
    int lane = threadIdx.x;
    int g = lane >> 4, hh = lane & 15;
    const float* W = (g==0) ? Wf : (g==1) ? Wi : (g==2) ? Wc : Wo;
    float U[HID];
    #pragma unroll
    for (int k = 0; k < HID; ++k) U[k] = W[hh*IN + EMB + k];
    float hA = h0[hh], CA = C0[hh];      // dir 0 (forward)
    float hB = h0[hh], CB = C0[hh];      // dir 1 (backward)
    int sbA = b, sbB = (S-1)*B + b;
    float xnA = xw[sbA*64 + lane];
    float xnB = xw[sbB*64 + lane];
    for (int step = 0; step < S; ++step) {
        float pA = xnA, pB = xnB;
        if (step + 1 < S) {                      // prefetch next x-contribs
            xnA = xw[(sbA + B)*64 + lane];
            xnB = xw[(sbB - B)*64 + lane];
        }
        if (g == 0) {                            // store h BEFORE update
            hcatB[sbA*CH + hh]       = __float2bfloat16(hA);
            hcatB[sbB*CH + HID + hh] = __float2bfloat16(hB);
        }
        float qA0=0.f,qA1=0.f,qA2=0.f,qA3=0.f;
        float qB0=0.f,qB1=0.f,qB2=0.f,qB3=0.f;
        #pragma unroll
        for (int k = 0; k < HID; k += 4) {       // 4 indep chains x 2 streams
            qA0 += U[k  ]*bcast(hA, k  );  qB0 += U[k  ]*bcast(hB, k  );
            qA1 += U[k+1]*bcast(hA, k+1);  qB1 += U[k+1]*bcast(hB, k+1);
            qA2 += U[k+2]*bcast(hA, k+2);  qB2 += U[k+2]*bcast(hB, k+2);
            qA3 += U[k+3]*bcast(hA, k+3);  qB3 += U[k+3]*bcast(hB, k+3);
        }
        pA += (qA0+qA1) + (qA2+qA3);
        pB += (qB0+qB1) + (qB2+qB3);
        float tA = (g==2) ? pA+pA : pA;
        float tB = (g==2) ? pB+pB : pB;
        float eA = __expf(-tA), eB = __expf(-tB);
        float sA = rcp_fast(1.f + eA), sB = rcp_fast(1.f + eB);
        float aA = (g==2) ? sA+sA-1.f : sA;
        float aB = (g==2) ? sB+sB-1.f : sB;
        float fgA = __shfl(aA,      hh, 64), fgB = __shfl(aB,      hh, 64);
        float igA = __shfl(aA, 16 + hh, 64), igB = __shfl(aB, 16 + hh, 64);
        float cgA = __shfl(aA, 32 + hh, 64), cgB = __shfl(aB, 32 + hh, 64);
        float ogA = __shfl(aA, 48 + hh, 64), ogB = __shfl(aB, 48 + hh, 64);
        CA = fgA*CA + igA*cgA;
        CB = fgB*CB + igB*cgB;
        float e2A = __expf(-(CA+CA));            // tanh(C) = 2*sigm(2C)-1
        float e2B = __expf(-(CB+CB));
        hA = ogA*(2.f*rcp_fast(1.f + e2A) - 1.f);
        hB = ogB*(2.f*rcp_fast(1.f + e2B) - 1.f);
        sbA += B; sbB -= B;
    }
}

// ---- kA: sum exp(logit) per row. Group-of-5 pipeline: all 15 loads of the
// next 5-tile group issue before computing the current group (~1200cy of
// MFMA+exp work covers even HBM-class latency within one wave). ----------
__global__ __launch_bounds__(256) void kA(
    const __hip_bfloat16* __restrict__ hcatB, const __hip_bfloat16* __restrict__ WhoB,
    const float* __restrict__ bhoP, float* __restrict__ row_sums)
{
    int t = threadIdx.x, w = t >> 6, lane = t & 63;
    int l31 = lane & 31, half = lane >> 5;
    int r0 = (blockIdx.y*4 + w)*32;
    int n0 = blockIdx.x*NT_PER;
    if (n0 >= NT32) return;
    int n1 = (n0 + NT_PER < NT32) ? n0 + NT_PER : NT32;
    const short* hp = (const short*)hcatB + (r0 + l31)*CH + half*8;
    bf16x8 a0 = *(const bf16x8*)hp;
    bf16x8 a1 = *(const bf16x8*)(hp + 16);
    f32x16 acc;
    #pragma unroll
    for (int r = 0; r < 16; ++r) acc[r] = 0.f;
    const short* wb = (const short*)WhoB + (long)l31*CH + half*8;  // lane base
    int nmain = n0 + ((n1 - n0)/GRP)*GRP;

    bf16x8 cb0[GRP], cb1[GRP]; float cbv[GRP];
    if (n0 < nmain) {
        #pragma unroll
        for (int j = 0; j < GRP; ++j) {
            cb0[j] = *(const bf16x8*)(wb + (long)(n0+j)*32*CH);
            cb1[j] = *(const bf16x8*)(wb + (long)(n0+j)*32*CH + 16);
            cbv[j] = bhoP[(n0+j)*32 + l31];
        }
    }
    for (int ng = n0; ng < nmain; ng += GRP) {
        int pg = (ng + GRP < nmain) ? ng + GRP : ng;   // clamp on last group
        bf16x8 nb0[GRP], nb1[GRP]; float nbv[GRP];
        #pragma unroll
        for (int j = 0; j < GRP; ++j) {                // issue ALL next loads
            nb0[j] = *(const bf16x8*)(wb + (long)(pg+j)*32*CH);
            nb1[j] = *(const bf16x8*)(wb + (long)(pg+j)*32*CH + 16);
            nbv[j] = bhoP[(pg+j)*32 + l31];
        }
        #pragma unroll
        for (int j = 0; j < GRP; ++j) {                // compute current group
            f32x16 d;
            #pragma unroll
            for (int r = 0; r < 16; ++r) d[r] = cbv[j];    // bias-seeded
            d = __builtin_amdgcn_mfma_f32_32x32x16_bf16(a0, cb0[j], d, 0, 0, 0);
            d = __builtin_amdgcn_mfma_f32_32x32x16_bf16(a1, cb1[j], d, 0, 0, 0);
            #pragma unroll
            for (int r = 0; r < 16; ++r) acc[r] += __expf(d[r]);
        }
        #pragma unroll
        for (int j = 0; j < GRP; ++j) { cb0[j]=nb0[j]; cb1[j]=nb1[j]; cbv[j]=nbv[j]; }
    }
    for (int nt = nmain; nt < n1; ++nt) {              // tail (last strip only)
        bf16x8 b0 = *(const bf16x8*)(wb + (long)nt*32*CH);
        bf16x8 b1 = *(const bf16x8*)(wb + (long)nt*32*CH + 16);
        float bv = bhoP[nt*32 + l31];
        f32x16 d;
        #pragma unroll
        for (int r = 0; r < 16; ++r) d[r] = bv;
        d = __builtin_amdgcn_mfma_f32_32x32x16_bf16(a0, b0, d, 0, 0, 0);
        d = __builtin_amdgcn_mfma_f32_32x32x16_bf16(a1, b1, d, 0, 0, 0);
        #pragma unroll
        for (int r = 0; r < 16; ++r) acc[r] += __expf(d[r]);
    }
    #pragma unroll
    for (int off = 1; off < 32; off <<= 1) {        // reduce over 32-lane half
        #pragma unroll
        for (int r = 0; r < 16; ++r) acc[r] += __shfl_xor(acc[r], off);
    }
    if (l31 == 0) {
        #pragma unroll
        for (int r = 0; r < 16; ++r)
            atomicAdd(&row_sums[r0 + (r&3) + 8*(r>>2) + 4*half], acc[r]);
    }
}

// ---- kB: recompute logits, seed accum with (bias - logZ), store ----------
// Same group-of-5 pipeline. Regular (cached) stores: L2 write-combines the
// row-misaligned straddles; nt stores caused 2.2GB RMW fetch (round 1).
__global__ __launch_bounds__(256) void kB(
    const __hip_bfloat16* __restrict__ hcatB, const __hip_bfloat16* __restrict__ WhoB,
    const float* __restrict__ bhoP, const float* __restrict__ row_sums,
    float* __restrict__ out)
{
    int t = threadIdx.x, w = t >> 6, lane = t & 63;
    int l31 = lane & 31, half = lane >> 5;
    int r0 = (blockIdx.y*4 + w)*32;
    int n0 = blockIdx.x*NT_PER;
    if (n0 >= NT32) return;
    int n1 = (n0 + NT_PER < NT32) ? n0 + NT_PER : NT32;
    const short* hp = (const short*)hcatB + (r0 + l31)*CH + half*8;
    bf16x8 a0 = *(const bf16x8*)hp;
    bf16x8 a1 = *(const bf16x8*)(hp + 16);
    f32x16   lzr;
    unsigned obase[16];
    #pragma unroll
    for (int r = 0; r < 16; ++r) {
        int row = r0 + (r&3) + 8*(r>>2) + 4*half;
        lzr[r]   = logf(row_sums[row]);
        obase[r] = (unsigned)row*V + l31;           // max < 103M, fits u32
    }
    const short* wb = (const short*)WhoB + (long)l31*CH + half*8;  // lane base
    int nmain = n0 + ((n1 - n0)/GRP)*GRP;

    bf16x8 cb0[GRP], cb1[GRP]; float cbv[GRP];
    if (n0 < nmain) {
        #pragma unroll
        for (int j = 0; j < GRP; ++j) {
            cb0[j] = *(const bf16x8*)(wb + (long)(n0+j)*32*CH);
            cb1[j] = *(const bf16x8*)(wb + (long)(n0+j)*32*CH + 16);
            cbv[j] = bhoP[(n0+j)*32 + l31];
        }
    }
    for (int ng = n0; ng < nmain; ng += GRP) {
        int pg = (ng + GRP < nmain) ? ng + GRP : ng;   // clamp on last group
        bf16x8 nb0[GRP], nb1[GRP]; float nbv[GRP];
        #pragma unroll
        for (int j = 0; j < GRP; ++j) {                // issue ALL next loads
            nb0[j] = *(const bf16x8*)(wb + (long)(pg+j)*32*CH);
            nb1[j] = *(const bf16x8*)(wb + (long)(pg+j)*32*CH + 16);
            nbv[j] = bhoP[(pg+j)*32 + l31];
        }
        #pragma unroll
        for (int j = 0; j < GRP; ++j) {                // compute + store
            int v0 = (ng + j)*32;
            f32x16 d;
            #pragma unroll
            for (int r = 0; r < 16; ++r) d[r] = cbv[j] - lzr[r];
            d = __builtin_amdgcn_mfma_f32_32x32x16_bf16(a0, cb0[j], d, 0, 0, 0);
            d = __builtin_amdgcn_mfma_f32_32x32x16_bf16(a1, cb1[j], d, 0, 0, 0);
            if (v0 + l31 < V) {          // only last vocab tile partially OOB
                #pragma unroll
                for (int r = 0; r < 16; ++r) out[obase[r] + v0] = d[r];
            }
        }
        #pragma unroll
        for (int j = 0; j < GRP; ++j) { cb0[j]=nb0[j]; cb1[j]=nb1[j]; cbv[j]=nbv[j]; }
    }
    for (int nt = nmain; nt < n1; ++nt) {              // tail (last strip only)
        int v0 = nt*32;
        bf16x8 b0 = *(const bf16x8*)(wb + (long)nt*32*CH);
        bf16x8 b1 = *(const bf16x8*)(wb + (long)nt*32*CH + 16);
        float bv = bhoP[nt*32 + l31];
        f32x16 d;
        #pragma unroll
        for (int r = 0; r < 16; ++r) d[r] = bv - lzr[r];
        d = __builtin_amdgcn_mfma_f32_32x32x16_bf16(a0, b0, d, 0, 0, 0);
        d = __builtin_amdgcn_mfma_f32_32x32x16_bf16(a1, b1, d, 0, 0, 0);
        if (v0 + l31 < V) {
            #pragma unroll
            for (int r = 0; r < 16; ++r) out[obase[r] + v0] = d[r];
        }
    }
}

extern "C" void kernel_launch(void* const* d_in, const int* in_sizes, int n_in,
                              void* d_out, int out_size, void* d_ws, size_t ws_size,
                              hipStream_t stream)
{
    const int*   tok = (const int*)d_in[0];
    const float* emb = (const float*)d_in[1];
    const float* Wf  = (const float*)d_in[2];
    const float* bf  = (const float*)d_in[3];
    const float* Wi  = (const float*)d_in[4];
    const float* bi  = (const float*)d_in[5];
    const float* Wc  = (const float*)d_in[6];
    const float* bc  = (const float*)d_in[7];
    const float* Wo  = (const float*)d_in[8];
    const float* bo  = (const float*)d_in[9];
    const float* Who = (const float*)d_in[10];
    const float* bho = (const float*)d_in[11];
    const float* h0  = (const float*)d_in[12];
    const float* C0  = (const float*)d_in[13];
    float* out = (float*)d_out;

    char* p = (char*)d_ws;
    __hip_bfloat16* WhoB  = (__hip_bfloat16*)p; p += (size_t)VPAD*CH*2;  // 3.2 MB
    __hip_bfloat16* hcatB = (__hip_bfloat16*)p; p += (size_t)S*B*CH*2;   // 128 KB
    float* bhoP     = (float*)p; p += (size_t)VPAD*4;
    float* xw       = (float*)p; p += (size_t)S*B*64*4;
    float* row_sums = (float*)p;

    kprep<<<dim3(NB_CONV + NB_XW), dim3(256), 0, stream>>>(
        tok, emb, Wf, bf, Wi, bi, Wc, bc, Wo, bo, Who, bho,
        WhoB, bhoP, xw, row_sums);
    k2_scan<<<dim3(32), dim3(64), 0, stream>>>(xw, Wf, Wi, Wc, Wo, h0, C0, hcatB);
    dim3 g(NSTRIP, MT32/4);   // (32, 16) = 512 blocks = 2/CU uniform
    kA<<<g, dim3(256), 0, stream>>>(hcatB, WhoB, bhoP, row_sums);
    kB<<<g, dim3(256), 0, stream>>>(hcatB, WhoB, bhoP, row_sums, out);
}